// Round 5
// baseline (176.889 us; speedup 1.0000x reference)
//
#include <hip/hip_runtime.h>
#include <cstddef>
#include <cstdint>

typedef float f32x4 __attribute__((ext_vector_type(4)));
typedef __bf16 bf16x8 __attribute__((ext_vector_type(8)));

#define MFMA_B16(a, b, c) __builtin_amdgcn_mfma_f32_16x16x32_bf16(a, b, c, 0, 0, 0)

// ---- d_ws fragment layout (bytes) ----
// L0  : [kt=4][nt=4][pl=2][lane=64][16B]  = 32768   (W_in x-part, K=128)
// WV  : [nt=4][pl=2][lane][16B]           =  8192   (W_in valid-part, K=32)
// ENC : [l=4][kt=2][nt=4][pl=2][lane][16B]= 65536
// OUT : [kt=2][nt=2][pl=2][lane][16B]     =  8192
#define OFF_L0   0u
#define OFF_WV   32768u
#define OFF_ENC  40960u
#define OFF_OUT  106496u

// ---- LDS layout (per block = 1 wave = 16 elements) ----
#define XB_OFF   0        // x    [16][512B] f32, swizzled
#define AH_OFF   8192     // act hi [16][128B] bf16, swizzled
#define AL_OFF   10240    // act lo (valid plane overlays before layer0)
#define WS_OFF   12288    // w solve [16][33] f32
#define SMEM_SZ  14400

__device__ __forceinline__ int xadr(int e, int b) { return (e << 9) | (b ^ ((e & 7) << 4)); }
__device__ __forceinline__ int aadr(int e, int b) { return (e << 7) | (b ^ ((e & 7) << 4)); }

// =====================  weight prep: fp32 -> bf16 hi/lo B-fragments  =====================
__global__ __launch_bounds__(256)
void prep_frags(const float* __restrict__ W_in, const float* __restrict__ W_enc,
                const float* __restrict__ W_out, unsigned* __restrict__ P) {
  const int idx = blockIdx.x * 256 + threadIdx.x;   // one u32 (2 bf16) per thread
  if (idx >= 28672) return;
  const int t = idx & 3;
  const int lane = (idx >> 2) & 63;
  const int g = lane >> 4, c = lane & 15;
  const int j0 = t << 1;
  int pl;
  float w0, w1;
  if (idx < 8192) {                       // L0 x-part: B[k][n], n = 4c+nt, k = kt*32+8g+j
    const int rest = idx >> 8;
    pl = rest & 1;
    const int nt = (rest >> 1) & 3;
    const int kt = rest >> 3;
    const int n = 4 * c + nt;
    const int k = kt * 32 + g * 8 + j0;
    const int m = k >> 2, q = k & 3;      // W'[n][k] = W_in[n][5m+q]
    w0 = W_in[n * 160 + 5 * m + q];
    w1 = W_in[n * 160 + 5 * m + q + 1];
  } else if (idx < 10240) {               // WV valid-part: k = m
    const int rest = (idx - 8192) >> 8;
    pl = rest & 1;
    const int nt = rest >> 1;
    const int n = 4 * c + nt;
    const int m = g * 8 + j0;
    w0 = W_in[n * 160 + 5 * m + 4];
    w1 = W_in[n * 160 + 5 * (m + 1) + 4];
  } else if (idx < 26624) {               // ENC
    const int rel = idx - 10240;
    const int l = rel >> 12;
    const int rest = (rel & 4095) >> 8;
    pl = rest & 1;
    const int nt = (rest >> 1) & 3;
    const int kt = rest >> 3;
    const int n = 4 * c + nt;
    const int k = kt * 32 + g * 8 + j0;
    w0 = W_enc[(l * 64 + n) * 64 + k];
    w1 = W_enc[(l * 64 + n) * 64 + k + 1];
  } else {                                // OUT (plain cols m = 16nt+c)
    const int rel = idx - 26624;
    const int rest = rel >> 8;
    pl = rest & 1;
    const int nt = (rest >> 1) & 1;
    const int kt = rest >> 2;
    const int mcol = 16 * nt + c;
    const int k = kt * 32 + g * 8 + j0;
    w0 = W_out[mcol * 64 + k];
    w1 = W_out[mcol * 64 + k + 1];
  }
  unsigned short u0, u1;
  if (pl == 0) {
    u0 = __builtin_bit_cast(unsigned short, (__bf16)w0);
    u1 = __builtin_bit_cast(unsigned short, (__bf16)w1);
  } else {
    const __bf16 h0 = (__bf16)w0, h1 = (__bf16)w1;
    u0 = __builtin_bit_cast(unsigned short, (__bf16)(w0 - (float)h0));
    u1 = __builtin_bit_cast(unsigned short, (__bf16)(w1 - (float)h1));
  }
  P[idx] = (unsigned)u0 | ((unsigned)u1 << 16);
}

// ---- pipeline macros: load granule (8 frags = 8KB) into a named register set ----
#define LOADG(R, base) do { \
  const char* p_ = wf + (base) + lane * 16; \
  R##0 = *(const bf16x8*)(p_); \
  R##1 = *(const bf16x8*)(p_ + 1024); \
  R##2 = *(const bf16x8*)(p_ + 2048); \
  R##3 = *(const bf16x8*)(p_ + 3072); \
  R##4 = *(const bf16x8*)(p_ + 4096); \
  R##5 = *(const bf16x8*)(p_ + 5120); \
  R##6 = *(const bf16x8*)(p_ + 6144); \
  R##7 = *(const bf16x8*)(p_ + 7168); \
} while (0)

#define TILE12(R, ah_, al_) do { \
  acc0 = MFMA_B16(ah_, R##0, acc0); acc0 = MFMA_B16(ah_, R##1, acc0); acc0 = MFMA_B16(al_, R##0, acc0); \
  acc1 = MFMA_B16(ah_, R##2, acc1); acc1 = MFMA_B16(ah_, R##3, acc1); acc1 = MFMA_B16(al_, R##2, acc1); \
  acc2 = MFMA_B16(ah_, R##4, acc2); acc2 = MFMA_B16(ah_, R##5, acc2); acc2 = MFMA_B16(al_, R##4, acc2); \
  acc3 = MFMA_B16(ah_, R##6, acc3); acc3 = MFMA_B16(ah_, R##7, acc3); acc3 = MFMA_B16(al_, R##6, acc3); \
} while (0)

#define L0STEP(R, kt) do { \
  bf16x8 ah_, al_; \
  xfrag(kt, ah_, al_); \
  TILE12(R, ah_, al_); \
} while (0)

#define WVSTEP(R) do { \
  const bf16x8 va_ = *(const bf16x8*)(smem + AL_OFF + aadr(c, g * 16)); \
  acc0 = MFMA_B16(va_, R##0, acc0); acc0 = MFMA_B16(va_, R##1, acc0); \
  acc1 = MFMA_B16(va_, R##2, acc1); acc1 = MFMA_B16(va_, R##3, acc1); \
  acc2 = MFMA_B16(va_, R##4, acc2); acc2 = MFMA_B16(va_, R##5, acc2); \
  acc3 = MFMA_B16(va_, R##6, acc3); acc3 = MFMA_B16(va_, R##7, acc3); \
} while (0)

#define ENCA(R, l) do { \
  { f32x4 t0_ = {ben[l][0], ben[l][0], ben[l][0], ben[l][0]}; acc0 = t0_; } \
  { f32x4 t1_ = {ben[l][1], ben[l][1], ben[l][1], ben[l][1]}; acc1 = t1_; } \
  { f32x4 t2_ = {ben[l][2], ben[l][2], ben[l][2], ben[l][2]}; acc2 = t2_; } \
  { f32x4 t3_ = {ben[l][3], ben[l][3], ben[l][3], ben[l][3]}; acc3 = t3_; } \
  const bf16x8 ah_ = *(const bf16x8*)(smem + AH_OFF + aadr(c, g * 16)); \
  const bf16x8 al_ = *(const bf16x8*)(smem + AL_OFF + aadr(c, g * 16)); \
  TILE12(R, ah_, al_); \
} while (0)

#define ENCB(R, l) do { \
  const bf16x8 ah_ = *(const bf16x8*)(smem + AH_OFF + aadr(c, 64 + g * 16)); \
  const bf16x8 al_ = *(const bf16x8*)(smem + AL_OFF + aadr(c, 64 + g * 16)); \
  TILE12(R, ah_, al_); \
  { f32x4 a4_[4] = {acc0, acc1, acc2, acc3}; act_store(a4_, aen[l]); } \
} while (0)

#define OUTSTEP(R) do { \
  const bf16x8 h0_ = *(const bf16x8*)(smem + AH_OFF + aadr(c, g * 16)); \
  const bf16x8 l0_ = *(const bf16x8*)(smem + AL_OFF + aadr(c, g * 16)); \
  const bf16x8 h1_ = *(const bf16x8*)(smem + AH_OFF + aadr(c, 64 + g * 16)); \
  const bf16x8 l1_ = *(const bf16x8*)(smem + AL_OFF + aadr(c, 64 + g * 16)); \
  wacc0 = MFMA_B16(h0_, R##0, wacc0); wacc0 = MFMA_B16(h0_, R##1, wacc0); wacc0 = MFMA_B16(l0_, R##0, wacc0); \
  wacc1 = MFMA_B16(h0_, R##2, wacc1); wacc1 = MFMA_B16(h0_, R##3, wacc1); wacc1 = MFMA_B16(l0_, R##2, wacc1); \
  wacc0 = MFMA_B16(h1_, R##4, wacc0); wacc0 = MFMA_B16(h1_, R##5, wacc0); wacc0 = MFMA_B16(l1_, R##4, wacc0); \
  wacc1 = MFMA_B16(h1_, R##6, wacc1); wacc1 = MFMA_B16(h1_, R##7, wacc1); wacc1 = MFMA_B16(l1_, R##6, wacc1); \
} while (0)

// =====================  fused MLP (split-bf16 MFMA) + WLS solve, reg-pipelined  =====================
__global__ __launch_bounds__(64, 2)
void wls_mfma(const float* __restrict__ x, const int* __restrict__ pad,
              const float* __restrict__ b_in, const float* __restrict__ a_in,
              const float* __restrict__ b_enc, const float* __restrict__ a_enc,
              const float* __restrict__ b_out, const char* __restrict__ wf,
              float* __restrict__ out) {
  __shared__ __align__(16) unsigned char smem[SMEM_SZ];
  const int lane = threadIdx.x;
  const int g = lane >> 4, c = lane & 15;
  const int ew = blockIdx.x << 4;          // 16 elements per wave/block

  // ---- hoisted scalar preloads (biases/alphas) ----
  const float bin[4] = {b_in[4 * c], b_in[4 * c + 1], b_in[4 * c + 2], b_in[4 * c + 3]};
  float ben[4][4];
  #pragma unroll
  for (int l = 0; l < 4; ++l)
    #pragma unroll
    for (int nt = 0; nt < 4; ++nt) ben[l][nt] = b_enc[l * 64 + 4 * c + nt];
  const float bo[2] = {b_out[c], b_out[16 + c]};
  const float ain = a_in[0];
  const float aen[4] = {a_enc[0], a_enc[1], a_enc[2], a_enc[3]};

  // ---- stage x rows (coalesced 1KB/round, swizzled wave-private LDS) ----
  {
    float4 xv[8];
    const char* src = (const char*)x + (size_t)ew * 512 + lane * 16;
    #pragma unroll
    for (int i = 0; i < 8; ++i) xv[i] = *(const float4*)(src + i * 1024);
    #pragma unroll
    for (int i = 0; i < 8; ++i) {
      const int off = i * 1024 + lane * 16;
      *(float4*)(smem + XB_OFF + xadr(off >> 9, off & 511)) = xv[i];
    }
  }
  // ---- stage valid = !pad as exact bf16 into AL plane ----
  {
    #pragma unroll
    for (int t = 0; t < 2; ++t) {
      const int el = lane >> 2;
      const int mq = (lane & 3) + (t << 2);
      const int4 pv = *(const int4*)(pad + (size_t)(ew + el) * 32 + (mq << 2));
      const unsigned ONE = 0x3F80u;  // bf16(1.0)
      const unsigned u0 = (pv.x ? 0u : ONE) | ((pv.y ? 0u : ONE) << 16);
      const unsigned u1 = (pv.z ? 0u : ONE) | ((pv.w ? 0u : ONE) << 16);
      *(uint2*)(smem + AL_OFF + aadr(el, mq << 3)) = make_uint2(u0, u1);
    }
  }

  auto xfrag = [&](int kt, bf16x8& ah, bf16x8& al) {
    const int b0 = kt * 128 + g * 32;
    const float4 v0 = *(const float4*)(smem + XB_OFF + xadr(c, b0));
    const float4 v1 = *(const float4*)(smem + XB_OFF + xadr(c, b0 + 16));
    const float vv[8] = {v0.x, v0.y, v0.z, v0.w, v1.x, v1.y, v1.z, v1.w};
    #pragma unroll
    for (int j = 0; j < 8; ++j) {
      const __bf16 h = (__bf16)vv[j];
      ah[j] = h;
      al[j] = (__bf16)(vv[j] - (float)h);
    }
  };
  // prelu -> split bf16 -> write act planes (n = 4c+nt permutation => contiguous 8B)
  auto act_store = [&](const f32x4* a4, float alpha) {
    #pragma unroll
    for (int r = 0; r < 4; ++r) {
      const int e = (g << 2) + r;
      unsigned hu[2], lu[2];
      #pragma unroll
      for (int q = 0; q < 2; ++q) {
        unsigned short hb[2], lb[2];
        #pragma unroll
        for (int s2 = 0; s2 < 2; ++s2) {
          float h = a4[2 * q + s2][r];
          h = (h >= 0.0f) ? h : alpha * h;
          const __bf16 hh = (__bf16)h;
          const __bf16 ll = (__bf16)(h - (float)hh);
          hb[s2] = __builtin_bit_cast(unsigned short, hh);
          lb[s2] = __builtin_bit_cast(unsigned short, ll);
        }
        hu[q] = (unsigned)hb[0] | ((unsigned)hb[1] << 16);
        lu[q] = (unsigned)lb[0] | ((unsigned)lb[1] << 16);
      }
      *(uint2*)(smem + AH_OFF + aadr(e, c * 8)) = make_uint2(hu[0], hu[1]);
      *(uint2*)(smem + AL_OFF + aadr(e, c * 8)) = make_uint2(lu[0], lu[1]);
    }
  };

  // ---- pipelined MLP: 14 granules, register double-buffer GA/GB ----
  bf16x8 GA0, GA1, GA2, GA3, GA4, GA5, GA6, GA7;
  bf16x8 GB0, GB1, GB2, GB3, GB4, GB5, GB6, GB7;
  f32x4 acc0, acc1, acc2, acc3;
  {
    f32x4 t0 = {bin[0], bin[0], bin[0], bin[0]}; acc0 = t0;
    f32x4 t1 = {bin[1], bin[1], bin[1], bin[1]}; acc1 = t1;
    f32x4 t2 = {bin[2], bin[2], bin[2], bin[2]}; acc2 = t2;
    f32x4 t3 = {bin[3], bin[3], bin[3], bin[3]}; acc3 = t3;
  }

  LOADG(GA, OFF_L0 + 0);          // G0 = L0 kt0
  LOADG(GB, OFF_L0 + 8192);       // G1 = L0 kt1
  L0STEP(GA, 0);
  LOADG(GA, OFF_L0 + 16384);      // G2 = L0 kt2
  L0STEP(GB, 1);
  LOADG(GB, OFF_L0 + 24576);      // G3 = L0 kt3
  L0STEP(GA, 2);
  LOADG(GA, OFF_WV);              // G4 = WV
  L0STEP(GB, 3);
  LOADG(GB, OFF_ENC + 0);         // G5 = E0a
  WVSTEP(GA);
  { f32x4 a4_[4] = {acc0, acc1, acc2, acc3}; act_store(a4_, ain); }   // layer-0 activation
  LOADG(GA, OFF_ENC + 8192);      // G6 = E0b
  ENCA(GB, 0);
  LOADG(GB, OFF_ENC + 16384);     // G7 = E1a
  ENCB(GA, 0);
  LOADG(GA, OFF_ENC + 24576);     // E1b
  ENCA(GB, 1);
  LOADG(GB, OFF_ENC + 32768);     // E2a
  ENCB(GA, 1);
  LOADG(GA, OFF_ENC + 40960);     // E2b
  ENCA(GB, 2);
  LOADG(GB, OFF_ENC + 49152);     // E3a
  ENCB(GA, 2);
  LOADG(GA, OFF_ENC + 57344);     // E3b
  ENCA(GB, 3);
  LOADG(GB, OFF_OUT);             // OUT
  ENCB(GA, 3);

  f32x4 wacc0, wacc1;
  {
    f32x4 t0 = {bo[0], bo[0], bo[0], bo[0]}; wacc0 = t0;
    f32x4 t1 = {bo[1], bo[1], bo[1], bo[1]}; wacc1 = t1;
  }
  OUTSTEP(GB);
  {
    float* ws = (float*)(smem + WS_OFF);
    #pragma unroll
    for (int r = 0; r < 4; ++r) {
      ws[((g << 2) + r) * 33 + c] = wacc0[r];
      ws[((g << 2) + r) * 33 + 16 + c] = wacc1[r];
    }
  }

  // ---- epilogue: G = A^T W^2 A (4x4 SPD), cvec = A^T W^2 r; 4 lanes per element ----
  {
    const int el = lane >> 2;
    const int p = lane & 3;
    const float* ws = (const float*)(smem + WS_OFF);
    float s[14];
    #pragma unroll
    for (int v = 0; v < 14; ++v) s[v] = 0.0f;
    #pragma unroll
    for (int t = 0; t < 8; ++t) {
      const int mm = (p << 3) + t;
      const float w = ws[el * 33 + mm];
      const float4 xv = *(const float4*)(smem + XB_OFF + xadr(el, mm << 4));
      const float r = xv.x;
      const float a1 = -xv.y, a2 = -xv.z, a3 = -xv.w;
      const float ww = w * w;
      const float w1 = ww * a1, w2 = ww * a2, w3 = ww * a3;
      s[0] += w1 * a1;  s[1] += w1 * a2;  s[2] += w1 * a3;  s[3] += w1;
      s[4] += w2 * a2;  s[5] += w2 * a3;  s[6] += w2;
      s[7] += w3 * a3;  s[8] += w3;
      s[9] += ww;
      s[10] += w1 * r;  s[11] += w2 * r;  s[12] += w3 * r;  s[13] += ww * r;
    }
    #pragma unroll
    for (int v = 0; v < 14; ++v) {
      s[v] += __shfl_xor(s[v], 1);
      s[v] += __shfl_xor(s[v], 2);
    }
    float Mt[4][5] = {
      {s[0], s[1], s[2], s[3], s[10]},
      {s[1], s[4], s[5], s[6], s[11]},
      {s[2], s[5], s[7], s[8], s[12]},
      {s[3], s[6], s[8], s[9], s[13]},
    };
    #pragma unroll
    for (int k = 0; k < 3; ++k) {
      const float inv = 1.0f / Mt[k][k];
      #pragma unroll
      for (int r2 = k + 1; r2 < 4; ++r2) {
        const float fk = Mt[r2][k] * inv;
        #pragma unroll
        for (int cc = k + 1; cc < 5; ++cc) Mt[r2][cc] -= fk * Mt[k][cc];
      }
    }
    const float th3 = Mt[3][4] / Mt[3][3];
    const float th2 = (Mt[2][4] - Mt[2][3] * th3) / Mt[2][2];
    const float th1 = (Mt[1][4] - Mt[1][3] * th3 - Mt[1][2] * th2) / Mt[1][1];
    const float th0 = (Mt[0][4] - Mt[0][3] * th3 - Mt[0][2] * th2 - Mt[0][1] * th1) / Mt[0][0];
    if (p == 0) {
      *(float4*)(out + (size_t)(ew + el) * 4) = make_float4(th0, th1, th2, th3);
    }
  }
}

extern "C" void kernel_launch(void* const* d_in, const int* in_sizes, int n_in,
                              void* d_out, int out_size, void* d_ws, size_t ws_size,
                              hipStream_t stream) {
  const float* x     = (const float*)d_in[0];
  const int*   pad   = (const int*)d_in[1];
  const float* W_in  = (const float*)d_in[2];
  const float* b_in  = (const float*)d_in[3];
  const float* a_in  = (const float*)d_in[4];
  const float* W_enc = (const float*)d_in[5];
  const float* b_enc = (const float*)d_in[6];
  const float* a_enc = (const float*)d_in[7];
  const float* W_out = (const float*)d_in[8];
  const float* b_out = (const float*)d_in[9];
  float* out = (float*)d_out;

  prep_frags<<<112, 256, 0, stream>>>(W_in, W_enc, W_out, (unsigned*)d_ws);
  // ATTRIBUTION ROUND: launch the identical kernel 8x (idempotent -- each
  // launch rewrites all of d_out from the same inputs). T_kernel =
  // (dur_this_round - dur_round4) / 7 isolates the true per-launch cost of
  // wls_mfma inside the graph, 7x above the ~3us run-to-run noise.
  for (int rep = 0; rep < 8; ++rep) {
    wls_mfma<<<2048, 64, 0, stream>>>(x, pad, b_in, a_in, b_enc, a_enc, b_out,
                                      (const char*)d_ws, out);
  }
}

// Round 6
// 95.258 us; speedup vs baseline: 1.8569x; 1.8569x over previous
//
#include <hip/hip_runtime.h>
#include <cstddef>
#include <cstdint>

typedef float f32x4 __attribute__((ext_vector_type(4)));
typedef __bf16 bf16x8 __attribute__((ext_vector_type(8)));

#define MFMA_B16(a, b, c) __builtin_amdgcn_mfma_f32_16x16x32_bf16(a, b, c, 0, 0, 0)

// ---- d_ws fragment layout (bytes) ----
// L0  : [kt=4][nt=4][pl=2][lane=64][16B]  = 32768   (W_in x-part, K=128)
// WV  : [nt=4][pl=2][lane][16B]           =  8192   (W_in valid-part, K=32)
// ENC : [l=4][kt=2][nt=4][pl=2][lane][16B]= 65536
// OUT : [kt=2][nt=2][pl=2][lane][16B]     =  8192
#define OFF_L0   0u
#define OFF_WV   32768u
#define OFF_ENC  40960u
#define OFF_OUT  106496u

// ---- LDS layout (per wave = 32 elements) ----
#define XB_OFF   0        // x    [32][512B] f32, swizzled           (16384 B)
#define AH_OFF   16384    // act hi [32][128B] bf16, swizzled        ( 4096 B)
#define AL_OFF   20480    // act lo (valid plane overlays pre-L0)    ( 4096 B)
#define WS_OFF   24576    // w solve [32][33] f32                    ( 4224 B)
#define PW       28800
#define SMEM_SZ  57600    // 2 waves/block

__device__ __forceinline__ int xadr(int e, int b) { return (e << 9) | (b ^ ((e & 7) << 4)); }
__device__ __forceinline__ int aadr(int e, int b) { return (e << 7) | (b ^ ((e & 7) << 4)); }

// =====================  weight prep: fp32 -> bf16 hi/lo B-fragments  =====================
__global__ __launch_bounds__(256)
void prep_frags(const float* __restrict__ W_in, const float* __restrict__ W_enc,
                const float* __restrict__ W_out, unsigned* __restrict__ P) {
  const int idx = blockIdx.x * 256 + threadIdx.x;   // one u32 (2 bf16) per thread
  if (idx >= 28672) return;
  const int t = idx & 3;
  const int lane = (idx >> 2) & 63;
  const int g = lane >> 4, c = lane & 15;
  const int j0 = t << 1;
  int pl;
  float w0, w1;
  if (idx < 8192) {                       // L0 x-part: B[k][n], n = 4c+nt, k = kt*32+8g+j
    const int rest = idx >> 8;
    pl = rest & 1;
    const int nt = (rest >> 1) & 3;
    const int kt = rest >> 3;
    const int n = 4 * c + nt;
    const int k = kt * 32 + g * 8 + j0;
    const int m = k >> 2, q = k & 3;      // W'[n][k] = W_in[n][5m+q]
    w0 = W_in[n * 160 + 5 * m + q];
    w1 = W_in[n * 160 + 5 * m + q + 1];
  } else if (idx < 10240) {               // WV valid-part: k = m
    const int rest = (idx - 8192) >> 8;
    pl = rest & 1;
    const int nt = rest >> 1;
    const int n = 4 * c + nt;
    const int m = g * 8 + j0;
    w0 = W_in[n * 160 + 5 * m + 4];
    w1 = W_in[n * 160 + 5 * (m + 1) + 4];
  } else if (idx < 26624) {               // ENC
    const int rel = idx - 10240;
    const int l = rel >> 12;
    const int rest = (rel & 4095) >> 8;
    pl = rest & 1;
    const int nt = (rest >> 1) & 3;
    const int kt = rest >> 3;
    const int n = 4 * c + nt;
    const int k = kt * 32 + g * 8 + j0;
    w0 = W_enc[(l * 64 + n) * 64 + k];
    w1 = W_enc[(l * 64 + n) * 64 + k + 1];
  } else {                                // OUT (plain cols m = 16nt+c)
    const int rel = idx - 26624;
    const int rest = rel >> 8;
    pl = rest & 1;
    const int nt = (rest >> 1) & 1;
    const int kt = rest >> 2;
    const int mcol = 16 * nt + c;
    const int k = kt * 32 + g * 8 + j0;
    w0 = W_out[mcol * 64 + k];
    w1 = W_out[mcol * 64 + k + 1];
  }
  unsigned short u0, u1;
  if (pl == 0) {
    u0 = __builtin_bit_cast(unsigned short, (__bf16)w0);
    u1 = __builtin_bit_cast(unsigned short, (__bf16)w1);
  } else {
    const __bf16 h0 = (__bf16)w0, h1 = (__bf16)w1;
    u0 = __builtin_bit_cast(unsigned short, (__bf16)(w0 - (float)h0));
    u1 = __builtin_bit_cast(unsigned short, (__bf16)(w1 - (float)h1));
  }
  P[idx] = (unsigned)u0 | ((unsigned)u1 << 16);
}

// ---- pipeline macros: load granule (8 frags = 8KB) into a named register set ----
#define LOADG(R, base) do { \
  const char* p_ = wf + (base) + lane * 16; \
  R##0 = *(const bf16x8*)(p_); \
  R##1 = *(const bf16x8*)(p_ + 1024); \
  R##2 = *(const bf16x8*)(p_ + 2048); \
  R##3 = *(const bf16x8*)(p_ + 3072); \
  R##4 = *(const bf16x8*)(p_ + 4096); \
  R##5 = *(const bf16x8*)(p_ + 5120); \
  R##6 = *(const bf16x8*)(p_ + 6144); \
  R##7 = *(const bf16x8*)(p_ + 7168); \
} while (0)

#define TILE12X(R, ah_, al_, q0, q1, q2, q3) do { \
  q0 = MFMA_B16(ah_, R##0, q0); q0 = MFMA_B16(ah_, R##1, q0); q0 = MFMA_B16(al_, R##0, q0); \
  q1 = MFMA_B16(ah_, R##2, q1); q1 = MFMA_B16(ah_, R##3, q1); q1 = MFMA_B16(al_, R##2, q1); \
  q2 = MFMA_B16(ah_, R##4, q2); q2 = MFMA_B16(ah_, R##5, q2); q2 = MFMA_B16(al_, R##4, q2); \
  q3 = MFMA_B16(ah_, R##6, q3); q3 = MFMA_B16(ah_, R##7, q3); q3 = MFMA_B16(al_, R##6, q3); \
} while (0)

#define L0STEP(R, kt) do { \
  bf16x8 ahA_, alA_, ahB_, alB_; \
  xfrag(0, kt, ahA_, alA_); \
  xfrag(1, kt, ahB_, alB_); \
  TILE12X(R, ahA_, alA_, accA0, accA1, accA2, accA3); \
  TILE12X(R, ahB_, alB_, accB0, accB1, accB2, accB3); \
} while (0)

#define WVSTEP(R) do { \
  const bf16x8 vaA_ = *(const bf16x8*)(smem + AL_OFF + aadr(c, g * 16)); \
  const bf16x8 vaB_ = *(const bf16x8*)(smem + AL_OFF + aadr(16 + c, g * 16)); \
  accA0 = MFMA_B16(vaA_, R##0, accA0); accA0 = MFMA_B16(vaA_, R##1, accA0); \
  accA1 = MFMA_B16(vaA_, R##2, accA1); accA1 = MFMA_B16(vaA_, R##3, accA1); \
  accA2 = MFMA_B16(vaA_, R##4, accA2); accA2 = MFMA_B16(vaA_, R##5, accA2); \
  accA3 = MFMA_B16(vaA_, R##6, accA3); accA3 = MFMA_B16(vaA_, R##7, accA3); \
  accB0 = MFMA_B16(vaB_, R##0, accB0); accB0 = MFMA_B16(vaB_, R##1, accB0); \
  accB1 = MFMA_B16(vaB_, R##2, accB1); accB1 = MFMA_B16(vaB_, R##3, accB1); \
  accB2 = MFMA_B16(vaB_, R##4, accB2); accB2 = MFMA_B16(vaB_, R##5, accB2); \
  accB3 = MFMA_B16(vaB_, R##6, accB3); accB3 = MFMA_B16(vaB_, R##7, accB3); \
} while (0)

#define SETBIAS(l) do { \
  { f32x4 t_ = {ben[l][0], ben[l][0], ben[l][0], ben[l][0]}; accA0 = t_; accB0 = t_; } \
  { f32x4 t_ = {ben[l][1], ben[l][1], ben[l][1], ben[l][1]}; accA1 = t_; accB1 = t_; } \
  { f32x4 t_ = {ben[l][2], ben[l][2], ben[l][2], ben[l][2]}; accA2 = t_; accB2 = t_; } \
  { f32x4 t_ = {ben[l][3], ben[l][3], ben[l][3], ben[l][3]}; accA3 = t_; accB3 = t_; } \
} while (0)

#define ENCA(R, l) do { \
  SETBIAS(l); \
  const bf16x8 ahA_ = *(const bf16x8*)(smem + AH_OFF + aadr(c, g * 16)); \
  const bf16x8 alA_ = *(const bf16x8*)(smem + AL_OFF + aadr(c, g * 16)); \
  const bf16x8 ahB_ = *(const bf16x8*)(smem + AH_OFF + aadr(16 + c, g * 16)); \
  const bf16x8 alB_ = *(const bf16x8*)(smem + AL_OFF + aadr(16 + c, g * 16)); \
  TILE12X(R, ahA_, alA_, accA0, accA1, accA2, accA3); \
  TILE12X(R, ahB_, alB_, accB0, accB1, accB2, accB3); \
} while (0)

#define ENCB(R, l) do { \
  const bf16x8 ahA_ = *(const bf16x8*)(smem + AH_OFF + aadr(c, 64 + g * 16)); \
  const bf16x8 alA_ = *(const bf16x8*)(smem + AL_OFF + aadr(c, 64 + g * 16)); \
  const bf16x8 ahB_ = *(const bf16x8*)(smem + AH_OFF + aadr(16 + c, 64 + g * 16)); \
  const bf16x8 alB_ = *(const bf16x8*)(smem + AL_OFF + aadr(16 + c, 64 + g * 16)); \
  TILE12X(R, ahA_, alA_, accA0, accA1, accA2, accA3); \
  TILE12X(R, ahB_, alB_, accB0, accB1, accB2, accB3); \
  { f32x4 a4_[4] = {accA0, accA1, accA2, accA3}; act_store(0, a4_, aen[l]); } \
  { f32x4 a4_[4] = {accB0, accB1, accB2, accB3}; act_store(1, a4_, aen[l]); } \
} while (0)

#define OUTSTEP(R) do { \
  const bf16x8 h0A_ = *(const bf16x8*)(smem + AH_OFF + aadr(c, g * 16)); \
  const bf16x8 l0A_ = *(const bf16x8*)(smem + AL_OFF + aadr(c, g * 16)); \
  const bf16x8 h1A_ = *(const bf16x8*)(smem + AH_OFF + aadr(c, 64 + g * 16)); \
  const bf16x8 l1A_ = *(const bf16x8*)(smem + AL_OFF + aadr(c, 64 + g * 16)); \
  waccA0 = MFMA_B16(h0A_, R##0, waccA0); waccA0 = MFMA_B16(h0A_, R##1, waccA0); waccA0 = MFMA_B16(l0A_, R##0, waccA0); \
  waccA1 = MFMA_B16(h0A_, R##2, waccA1); waccA1 = MFMA_B16(h0A_, R##3, waccA1); waccA1 = MFMA_B16(l0A_, R##2, waccA1); \
  waccA0 = MFMA_B16(h1A_, R##4, waccA0); waccA0 = MFMA_B16(h1A_, R##5, waccA0); waccA0 = MFMA_B16(l1A_, R##4, waccA0); \
  waccA1 = MFMA_B16(h1A_, R##6, waccA1); waccA1 = MFMA_B16(h1A_, R##7, waccA1); waccA1 = MFMA_B16(l1A_, R##6, waccA1); \
  const bf16x8 h0B_ = *(const bf16x8*)(smem + AH_OFF + aadr(16 + c, g * 16)); \
  const bf16x8 l0B_ = *(const bf16x8*)(smem + AL_OFF + aadr(16 + c, g * 16)); \
  const bf16x8 h1B_ = *(const bf16x8*)(smem + AH_OFF + aadr(16 + c, 64 + g * 16)); \
  const bf16x8 l1B_ = *(const bf16x8*)(smem + AL_OFF + aadr(16 + c, 64 + g * 16)); \
  waccB0 = MFMA_B16(h0B_, R##0, waccB0); waccB0 = MFMA_B16(h0B_, R##1, waccB0); waccB0 = MFMA_B16(l0B_, R##0, waccB0); \
  waccB1 = MFMA_B16(h0B_, R##2, waccB1); waccB1 = MFMA_B16(h0B_, R##3, waccB1); waccB1 = MFMA_B16(l0B_, R##2, waccB1); \
  waccB0 = MFMA_B16(h1B_, R##4, waccB0); waccB0 = MFMA_B16(h1B_, R##5, waccB0); waccB0 = MFMA_B16(l1B_, R##4, waccB0); \
  waccB1 = MFMA_B16(h1B_, R##6, waccB1); waccB1 = MFMA_B16(h1B_, R##7, waccB1); waccB1 = MFMA_B16(l1B_, R##6, waccB1); \
} while (0)

// =====================  fused MLP (split-bf16 MFMA) + WLS solve, 32 elems/wave  =====================
__global__ __launch_bounds__(128, 2)
void wls_mfma(const float* __restrict__ x, const int* __restrict__ pad,
              const float* __restrict__ b_in, const float* __restrict__ a_in,
              const float* __restrict__ b_enc, const float* __restrict__ a_enc,
              const float* __restrict__ b_out, const char* __restrict__ wf,
              float* __restrict__ out) {
  __shared__ __align__(16) unsigned char smem_all[SMEM_SZ];
  const int tid = threadIdx.x;
  const int wv = tid >> 6;
  const int lane = tid & 63;
  const int g = lane >> 4, c = lane & 15;
  unsigned char* smem = smem_all + wv * PW;
  const int ew = (blockIdx.x << 6) + (wv << 5);   // 32 elements per wave

  // ---- hoisted scalar preloads (biases/alphas) ----
  const float bin[4] = {b_in[4 * c], b_in[4 * c + 1], b_in[4 * c + 2], b_in[4 * c + 3]};
  float ben[4][4];
  #pragma unroll
  for (int l = 0; l < 4; ++l)
    #pragma unroll
    for (int nt = 0; nt < 4; ++nt) ben[l][nt] = b_enc[l * 64 + 4 * c + nt];
  const float bo[2] = {b_out[c], b_out[16 + c]};
  const float ain = a_in[0];
  const float aen[4] = {a_enc[0], a_enc[1], a_enc[2], a_enc[3]};

  // ---- stage x rows: 32 rows x 512B, two batches of 8KB (coalesced, swizzled) ----
  #pragma unroll
  for (int half = 0; half < 2; ++half) {
    float4 xv[8];
    const char* src = (const char*)x + (size_t)ew * 512 + half * 8192 + lane * 16;
    #pragma unroll
    for (int i = 0; i < 8; ++i) xv[i] = *(const float4*)(src + i * 1024);
    #pragma unroll
    for (int i = 0; i < 8; ++i) {
      const int off = half * 8192 + i * 1024 + lane * 16;
      *(float4*)(smem + XB_OFF + xadr(off >> 9, off & 511)) = xv[i];
    }
  }
  // ---- stage valid = !pad as exact bf16 into AL plane (4 rounds) ----
  #pragma unroll
  for (int t = 0; t < 4; ++t) {
    const int el = (t << 3) + (lane >> 3);
    const int mq = lane & 7;
    const int4 pv = *(const int4*)(pad + (size_t)(ew + el) * 32 + (mq << 2));
    const unsigned ONE = 0x3F80u;  // bf16(1.0)
    const unsigned u0 = (pv.x ? 0u : ONE) | ((pv.y ? 0u : ONE) << 16);
    const unsigned u1 = (pv.z ? 0u : ONE) | ((pv.w ? 0u : ONE) << 16);
    *(uint2*)(smem + AL_OFF + aadr(el, mq << 3)) = make_uint2(u0, u1);
  }

  auto xfrag = [&](int grp, int kt, bf16x8& ah, bf16x8& al) {
    const int e = (grp << 4) + c;
    const int b0 = kt * 128 + g * 32;
    const float4 v0 = *(const float4*)(smem + XB_OFF + xadr(e, b0));
    const float4 v1 = *(const float4*)(smem + XB_OFF + xadr(e, b0 + 16));
    const float vv[8] = {v0.x, v0.y, v0.z, v0.w, v1.x, v1.y, v1.z, v1.w};
    #pragma unroll
    for (int j = 0; j < 8; ++j) {
      const __bf16 h = (__bf16)vv[j];
      ah[j] = h;
      al[j] = (__bf16)(vv[j] - (float)h);
    }
  };
  // prelu -> split bf16 -> write act planes (n = 4c+nt permutation => contiguous 8B)
  auto act_store = [&](int grp, const f32x4* a4, float alpha) {
    #pragma unroll
    for (int r = 0; r < 4; ++r) {
      const int e = (grp << 4) + (g << 2) + r;
      unsigned hu[2], lu[2];
      #pragma unroll
      for (int q = 0; q < 2; ++q) {
        unsigned short hb[2], lb[2];
        #pragma unroll
        for (int s2 = 0; s2 < 2; ++s2) {
          float h = a4[2 * q + s2][r];
          h = (h >= 0.0f) ? h : alpha * h;
          const __bf16 hh = (__bf16)h;
          const __bf16 ll = (__bf16)(h - (float)hh);
          hb[s2] = __builtin_bit_cast(unsigned short, hh);
          lb[s2] = __builtin_bit_cast(unsigned short, ll);
        }
        hu[q] = (unsigned)hb[0] | ((unsigned)hb[1] << 16);
        lu[q] = (unsigned)lb[0] | ((unsigned)lb[1] << 16);
      }
      *(uint2*)(smem + AH_OFF + aadr(e, c * 8)) = make_uint2(hu[0], hu[1]);
      *(uint2*)(smem + AL_OFF + aadr(e, c * 8)) = make_uint2(lu[0], lu[1]);
    }
  };

  // ---- pipelined MLP: 14 granules, register double-buffer GA/GB ----
  bf16x8 GA0, GA1, GA2, GA3, GA4, GA5, GA6, GA7;
  bf16x8 GB0, GB1, GB2, GB3, GB4, GB5, GB6, GB7;
  f32x4 accA0, accA1, accA2, accA3, accB0, accB1, accB2, accB3;
  {
    f32x4 t0 = {bin[0], bin[0], bin[0], bin[0]}; accA0 = t0; accB0 = t0;
    f32x4 t1 = {bin[1], bin[1], bin[1], bin[1]}; accA1 = t1; accB1 = t1;
    f32x4 t2 = {bin[2], bin[2], bin[2], bin[2]}; accA2 = t2; accB2 = t2;
    f32x4 t3 = {bin[3], bin[3], bin[3], bin[3]}; accA3 = t3; accB3 = t3;
  }

  LOADG(GA, OFF_L0 + 0);          // L0 kt0
  LOADG(GB, OFF_L0 + 8192);       // L0 kt1
  L0STEP(GA, 0);
  LOADG(GA, OFF_L0 + 16384);      // L0 kt2
  L0STEP(GB, 1);
  LOADG(GB, OFF_L0 + 24576);      // L0 kt3
  L0STEP(GA, 2);
  LOADG(GA, OFF_WV);              // WV
  L0STEP(GB, 3);
  LOADG(GB, OFF_ENC + 0);         // E0a
  WVSTEP(GA);
  { f32x4 a4_[4] = {accA0, accA1, accA2, accA3}; act_store(0, a4_, ain); }
  { f32x4 a4_[4] = {accB0, accB1, accB2, accB3}; act_store(1, a4_, ain); }
  LOADG(GA, OFF_ENC + 8192);      // E0b
  ENCA(GB, 0);
  LOADG(GB, OFF_ENC + 16384);     // E1a
  ENCB(GA, 0);
  LOADG(GA, OFF_ENC + 24576);     // E1b
  ENCA(GB, 1);
  LOADG(GB, OFF_ENC + 32768);     // E2a
  ENCB(GA, 1);
  LOADG(GA, OFF_ENC + 40960);     // E2b
  ENCA(GB, 2);
  LOADG(GB, OFF_ENC + 49152);     // E3a
  ENCB(GA, 2);
  LOADG(GA, OFF_ENC + 57344);     // E3b
  ENCA(GB, 3);
  LOADG(GB, OFF_OUT);             // OUT
  ENCB(GA, 3);

  f32x4 waccA0, waccA1, waccB0, waccB1;
  {
    f32x4 t0 = {bo[0], bo[0], bo[0], bo[0]}; waccA0 = t0; waccB0 = t0;
    f32x4 t1 = {bo[1], bo[1], bo[1], bo[1]}; waccA1 = t1; waccB1 = t1;
  }
  OUTSTEP(GB);
  {
    float* ws = (float*)(smem + WS_OFF);
    #pragma unroll
    for (int r = 0; r < 4; ++r) {
      ws[((g << 2) + r) * 33 + c] = waccA0[r];
      ws[((g << 2) + r) * 33 + 16 + c] = waccA1[r];
      ws[(16 + (g << 2) + r) * 33 + c] = waccB0[r];
      ws[(16 + (g << 2) + r) * 33 + 16 + c] = waccB1[r];
    }
  }

  // ---- epilogue: G = A^T W^2 A (4x4 SPD), cvec = A^T W^2 r; 4 lanes/elem, 2 passes ----
  #pragma unroll
  for (int it = 0; it < 2; ++it) {
    const int el = (it << 4) + (lane >> 2);
    const int p = lane & 3;
    const float* ws = (const float*)(smem + WS_OFF);
    float s[14];
    #pragma unroll
    for (int v = 0; v < 14; ++v) s[v] = 0.0f;
    #pragma unroll
    for (int t = 0; t < 8; ++t) {
      const int mm = (p << 3) + t;
      const float w = ws[el * 33 + mm];
      const float4 xv = *(const float4*)(smem + XB_OFF + xadr(el, mm << 4));
      const float r = xv.x;
      const float a1 = -xv.y, a2 = -xv.z, a3 = -xv.w;
      const float ww = w * w;
      const float w1 = ww * a1, w2 = ww * a2, w3 = ww * a3;
      s[0] += w1 * a1;  s[1] += w1 * a2;  s[2] += w1 * a3;  s[3] += w1;
      s[4] += w2 * a2;  s[5] += w2 * a3;  s[6] += w2;
      s[7] += w3 * a3;  s[8] += w3;
      s[9] += ww;
      s[10] += w1 * r;  s[11] += w2 * r;  s[12] += w3 * r;  s[13] += ww * r;
    }
    #pragma unroll
    for (int v = 0; v < 14; ++v) {
      s[v] += __shfl_xor(s[v], 1);
      s[v] += __shfl_xor(s[v], 2);
    }
    float Mt[4][5] = {
      {s[0], s[1], s[2], s[3], s[10]},
      {s[1], s[4], s[5], s[6], s[11]},
      {s[2], s[5], s[7], s[8], s[12]},
      {s[3], s[6], s[8], s[9], s[13]},
    };
    #pragma unroll
    for (int k = 0; k < 3; ++k) {
      const float inv = 1.0f / Mt[k][k];
      #pragma unroll
      for (int r2 = k + 1; r2 < 4; ++r2) {
        const float fk = Mt[r2][k] * inv;
        #pragma unroll
        for (int cc = k + 1; cc < 5; ++cc) Mt[r2][cc] -= fk * Mt[k][cc];
      }
    }
    const float th3 = Mt[3][4] / Mt[3][3];
    const float th2 = (Mt[2][4] - Mt[2][3] * th3) / Mt[2][2];
    const float th1 = (Mt[1][4] - Mt[1][3] * th3 - Mt[1][2] * th2) / Mt[1][1];
    const float th0 = (Mt[0][4] - Mt[0][3] * th3 - Mt[0][2] * th2 - Mt[0][1] * th1) / Mt[0][0];
    if (p == 0) {
      *(float4*)(out + (size_t)(ew + el) * 4) = make_float4(th0, th1, th2, th3);
    }
  }
}

extern "C" void kernel_launch(void* const* d_in, const int* in_sizes, int n_in,
                              void* d_out, int out_size, void* d_ws, size_t ws_size,
                              hipStream_t stream) {
  const float* x     = (const float*)d_in[0];
  const int*   pad   = (const int*)d_in[1];
  const float* W_in  = (const float*)d_in[2];
  const float* b_in  = (const float*)d_in[3];
  const float* a_in  = (const float*)d_in[4];
  const float* W_enc = (const float*)d_in[5];
  const float* b_enc = (const float*)d_in[6];
  const float* a_enc = (const float*)d_in[7];
  const float* W_out = (const float*)d_in[8];
  const float* b_out = (const float*)d_in[9];
  float* out = (float*)d_out;

  prep_frags<<<112, 256, 0, stream>>>(W_in, W_enc, W_out, (unsigned*)d_ws);
  wls_mfma<<<512, 128, 0, stream>>>(x, pad, b_in, a_in, b_enc, a_enc, b_out,
                                    (const char*)d_ws, out);
}